// Round 2
// baseline (176.978 us; speedup 1.0000x reference)
//
#include <hip/hip_runtime.h>

// Enframe: out[bc, k, t] = x[bc, t*HOP + k].  BC=16, S=480000, FL=2048,
// HOP=512, T=934.  Decompose k = h*HOP + r (h in [0,4), r in [0,HOP)):
//   out[bc, h*HOP + r, t] = y[t+h, r],  y = x viewed as rows of HOP floats.
// => 4 shifted (T x 512) -> (512 x T) transposes. Do it as an LDS transpose:
//   load tile (67 rows x 64 r) coalesced along r  (input-contiguous),
//   store tile (4h x 64 r x 64 t) coalesced along t (output-contiguous).
// LDS stride 65: load-phase banks 2-way, store-phase banks 2-way (free, m136).
// Round 0 lesson: lane-strided reads (2048B apart) = 64 lines per load instr,
// request-rate bound at 0.9 TB/s. Both phases must be lane-contiguous.

constexpr int FL  = 2048;
constexpr int HOP = 512;
constexpr int TT  = 64;           // t-tile
constexpr int RT  = 64;           // r-tile
constexpr int ROWS = TT + 3;      // 67: need rows t..t+3
constexpr int LSTR = RT + 1;      // 65: LDS row stride (bank-conflict-free)

__global__ __launch_bounds__(256)
void enframe_kernel(const float* __restrict__ x, float* __restrict__ out,
                    int S, int T) {
    __shared__ float lds[ROWS * LSTR];

    const int bc = blockIdx.x;          // 0..15
    const int t0 = blockIdx.y * TT;     // t-tile origin
    const int r0 = blockIdx.z * RT;     // r-tile origin
    const int tid = threadIdx.x;

    // ---- load phase: 67 rows x 64 floats, float4-coalesced along r ----
    {
        const int rg   = tid & 15;      // 16 float4s cover one 64-float row
        const int row0 = tid >> 4;      // 16 rows per pass
        const float* xb = x + (size_t)bc * S;
#pragma unroll
        for (int p = 0; p < 5; ++p) {
            const int row = p * 16 + row0;
            if (row < ROWS) {
                const int trow = t0 + row;
                // only load rows fully inside the signal
                if ((size_t)trow * HOP + r0 + RT <= (size_t)S) {
                    const float4 v = *(const float4*)(xb + (size_t)trow * HOP + r0 + rg * 4);
                    float* l = lds + row * LSTR + rg * 4;
                    l[0] = v.x; l[1] = v.y; l[2] = v.z; l[3] = v.w;
                }
            }
        }
    }
    __syncthreads();

    // ---- store phase: lanes along t (output-contiguous), scalar nt stores ----
    const int t_local = tid & 63;       // wave-contiguous t
    const int idx     = tid >> 6;       // wave id picks r within group of 4
    const int t       = t0 + t_local;
    if (t < T) {
        float* ob = out + (size_t)bc * FL * T + t;
#pragma unroll
        for (int rb = 0; rb < RT; rb += 4) {
            const int rr = rb + idx;
            const int k0 = r0 + rr;
#pragma unroll
            for (int h = 0; h < 4; ++h) {
                const float v = lds[(t_local + h) * LSTR + rr];
                __builtin_nontemporal_store(v, ob + (size_t)(h * HOP + k0) * T);
            }
        }
    }
}

extern "C" void kernel_launch(void* const* d_in, const int* in_sizes, int n_in,
                              void* d_out, int out_size, void* d_ws, size_t ws_size,
                              hipStream_t stream) {
    const float* x = (const float*)d_in[0];
    float* out = (float*)d_out;
    const int BC = 16;                  // B*C = 8*2
    const int S  = in_sizes[0] / BC;    // 480000
    const int T  = (S - FL) / HOP + 1;  // 934
    const int t_tiles = (T + TT - 1) / TT;   // 15
    const int r_tiles = HOP / RT;            // 8
    dim3 grid(BC, (unsigned)t_tiles, (unsigned)r_tiles);
    enframe_kernel<<<grid, 256, 0, stream>>>(x, out, S, T);
}

// Round 3
// 152.468 us; speedup vs baseline: 1.1608x; 1.1608x over previous
//
#include <hip/hip_runtime.h>

// Enframe: out[bc, k, t] = x[bc, t*HOP + k].  BC=16, S=480000, FL=2048,
// HOP=512, T=934.  k = h*HOP + r (h in [0,4), r in [0,HOP)):
//   out[bc, h*HOP + r, t] = row (t+h), col r of x viewed as rows of HOP.
// LDS transpose per block: load (67 rows x 64 r) coalesced along r, emit
// (4h x 64 r) x 64 t coalesced along t.
//
// R2 lesson: scalar nt stores were the bottleneck (R0 divergent-read and R2
// coalesced-read kernels timed identically -> store-path bound). This round:
//   - float4 stores along t: 4x fewer store instrs, 1KB/wave-instr
//   - no nontemporal: rows are misaligned (T=934 -> 3736B stride), L2 must
//     merge partial lines across adjacent t-tiles (same bc -> same XCD since
//     linear block id % 8 == bc % 8 with grid.x=16)

constexpr int FL  = 2048;
constexpr int HOP = 512;
constexpr int TT  = 64;           // t-tile
constexpr int RT  = 64;           // r-tile
constexpr int ROWS = TT + 3;      // 67: rows t..t+3
constexpr int LSTR = RT + 1;      // 65: LDS row stride (2-way banks = free)

__global__ __launch_bounds__(256)
void enframe_kernel(const float* __restrict__ x, float* __restrict__ out,
                    int S, int T) {
    __shared__ float lds[ROWS * LSTR];

    const int bc = blockIdx.x;          // 0..15
    const int t0 = blockIdx.y * TT;
    const int r0 = blockIdx.z * RT;
    const int tid = threadIdx.x;

    // ---- load: 67 rows x 64 floats, float4-coalesced along r ----
    {
        const int rg   = tid & 15;      // 16 float4 per 64-float row
        const int row0 = tid >> 4;
        const float* xb = x + (size_t)bc * S;
#pragma unroll
        for (int p = 0; p < 5; ++p) {
            const int row = p * 16 + row0;
            if (row < ROWS) {
                const size_t base = (size_t)(t0 + row) * HOP + r0;
                if (base + RT <= (size_t)S) {
                    const float4 v = *(const float4*)(xb + base + rg * 4);
                    float* l = lds + row * LSTR + rg * 4;
                    l[0] = v.x; l[1] = v.y; l[2] = v.z; l[3] = v.w;
                }
            }
        }
    }
    __syncthreads();

    // ---- store: float4 along t (lanes: 16 t-groups x 4 k-offsets) ----
    const int tg = tid & 15;            // t-group (4 t's each)
    const int ko = tid >> 4;            // 0..15: k offset within r-tile step
    const int tl = tg * 4;              // local t base
    const int t  = t0 + tl;
    float* ob = out + (size_t)bc * FL * T;
    const bool full = (t + 3 < T);
#pragma unroll
    for (int rb = 0; rb < RT; rb += 16) {
        const int rr = rb + ko;         // local r
        const int kb = r0 + rr;
#pragma unroll
        for (int h = 0; h < 4; ++h) {
            const int k = h * HOP + kb;
            const float* l = lds + (tl + h) * LSTR + rr;
            if (full) {
                float4 v = { l[0 * LSTR], l[1 * LSTR], l[2 * LSTR], l[3 * LSTR] };
                *(float4*)(ob + (size_t)k * T + t) = v;
            } else {
#pragma unroll
                for (int j = 0; j < 4; ++j)
                    if (t + j < T) ob[(size_t)k * T + t + j] = l[j * LSTR];
            }
        }
    }
}

extern "C" void kernel_launch(void* const* d_in, const int* in_sizes, int n_in,
                              void* d_out, int out_size, void* d_ws, size_t ws_size,
                              hipStream_t stream) {
    const float* x = (const float*)d_in[0];
    float* out = (float*)d_out;
    const int BC = 16;                  // B*C = 8*2
    const int S  = in_sizes[0] / BC;    // 480000
    const int T  = (S - FL) / HOP + 1;  // 934
    const int t_tiles = (T + TT - 1) / TT;   // 15
    const int r_tiles = HOP / RT;            // 8
    dim3 grid(BC, (unsigned)t_tiles, (unsigned)r_tiles);
    enframe_kernel<<<grid, 256, 0, stream>>>(x, out, S, T);
}